// Round 1
// baseline (430.011 us; speedup 1.0000x reference)
//
#include <hip/hip_runtime.h>
#include <hip/hip_bf16.h>
#include <math.h>

#define NN 131072
#define BSEG 16
#define CCH 128
#define KK 16
#define EPSF 1e-9f

// d_out layout (floats): out[B*K*C]=32768 | s[N*K]=2097152 | mu[B*K*2]=512 | losses[9]
#define OFF_S   32768
#define OFF_MU  2129920
#define OFF_L   2130432

// ws layout (floats): [0..255] sum_s[b*16+k] | [256..767] sum_s_pos[b*32+k*2+d] | [768] ent_sum | [769] batch-is-int64 flag

__device__ __forceinline__ int load_batch(const void* bptr, int n, int is64) {
    if (is64) return (int)((const long long*)bptr)[n];
    return ((const int*)bptr)[n];
}

__device__ __forceinline__ float wave_sum(float v) {
#pragma unroll
    for (int o = 32; o > 0; o >>= 1) v += __shfl_xor(v, o, 64);
    return v;
}

__global__ void k_detect(const int* __restrict__ b32, float* __restrict__ flag) {
    if (threadIdx.x == 0 && blockIdx.x == 0)
        flag[0] = (b32[NN - 1] == 0) ? 1.0f : 0.0f;  // int64 high word at odd idx => 0
}

__global__ void k_zero(float* __restrict__ out0, float* __restrict__ ws) {
    int i = blockIdx.x * 256 + threadIdx.x;
    if (i < BSEG * KK * CCH) out0[i] = 0.0f;
    if (i < 769) ws[i] = 0.0f;   // keep ws[769] (flag) intact
}

__global__ __launch_bounds__(256, 2) void k_mlp(
    const float* __restrict__ x, const void* __restrict__ batch,
    const float* __restrict__ pos, const float* __restrict__ gumbel,
    const float* __restrict__ W1, const float* __restrict__ b1,
    const float* __restrict__ W2, const float* __restrict__ b2,
    const float* __restrict__ scaling, const float* __restrict__ active_mask,
    float* __restrict__ s_out, float* __restrict__ ws)
{
    const int n = blockIdx.x * 256 + threadIdx.x;
    const int lane = threadIdx.x & 63;
    const int is64 = (int)ws[769];

    // ---- load x row into registers ----
    float xr[CCH];
    const float4* xv = (const float4*)(x + (size_t)n * CCH);
#pragma unroll
    for (int i = 0; i < CCH / 4; i++) {
        float4 t = xv[i];
        xr[4 * i] = t.x; xr[4 * i + 1] = t.y; xr[4 * i + 2] = t.z; xr[4 * i + 3] = t.w;
    }

    // ---- MLP: logits[k] = sum_j relu(x.W1[j]+b1[j]) * W2[k][j] ----
    float lacc[KK];
#pragma unroll
    for (int k = 0; k < KK; k++) lacc[k] = 0.0f;

#pragma unroll 1
    for (int j = 0; j < CCH; j++) {
        const float* w = W1 + j * CCH;   // uniform address -> s_load
        float a0 = 0.f, a1 = 0.f, a2 = 0.f, a3 = 0.f;
#pragma unroll
        for (int c = 0; c < CCH; c += 4) {
            a0 = fmaf(xr[c],     w[c],     a0);
            a1 = fmaf(xr[c + 1], w[c + 1], a1);
            a2 = fmaf(xr[c + 2], w[c + 2], a2);
            a3 = fmaf(xr[c + 3], w[c + 3], a3);
        }
        float hj = (a0 + a1) + (a2 + a3) + b1[j];
        hj = fmaxf(hj, 0.0f);
#pragma unroll
        for (int k = 0; k < KK; k++)
            lacc[k] = fmaf(hj, W2[k * CCH + j], lacc[k]);
    }

    // ---- mask, gumbel, softmax ----
    float garr[KK];
    const float4* gv = (const float4*)(gumbel + (size_t)n * KK);
#pragma unroll
    for (int i = 0; i < KK / 4; i++) {
        float4 t = gv[i];
        garr[4 * i] = t.x; garr[4 * i + 1] = t.y; garr[4 * i + 2] = t.z; garr[4 * i + 3] = t.w;
    }
    const float sc = scaling[0];
    float lg[KK];
    float m = -1e30f;
#pragma unroll
    for (int k = 0; k < KK; k++) {
        float l = (lacc[k] + b2[k]) * sc;
        if (active_mask[k] == 0.0f) l = -1e9f;
        l = l + garr[k];          // TAU == 1.0
        lg[k] = l;
        m = fmaxf(m, l);
    }
    float ssum = 0.0f;
#pragma unroll
    for (int k = 0; k < KK; k++) { lg[k] = expf(lg[k] - m); ssum += lg[k]; }
    const float inv = 1.0f / ssum;
    float s[KK];
#pragma unroll
    for (int k = 0; k < KK; k++) s[k] = lg[k] * inv;

    // ---- write s ----
    float4* sv = (float4*)(s_out + (size_t)n * KK);
#pragma unroll
    for (int i = 0; i < KK / 4; i++) {
        float4 t; t.x = s[4 * i]; t.y = s[4 * i + 1]; t.z = s[4 * i + 2]; t.w = s[4 * i + 3];
        sv[i] = t;
    }

    // ---- per-node loss partials + segment sums ----
    float ent = 0.0f;
#pragma unroll
    for (int k = 0; k < KK; k++) ent += s[k] * logf(s[k] + EPSF);

    const float2 p = ((const float2*)pos)[n];
    const int bi = load_batch(batch, n, is64);
    const int b0 = __shfl(bi, 0, 64);
    const bool uni = (__all(bi == b0) != 0);

    if (uni) {
#pragma unroll
        for (int k = 0; k < KK; k++) {
            float v = wave_sum(s[k]);
            if (lane == 0) atomicAdd(&ws[b0 * KK + k], v);
        }
#pragma unroll
        for (int k = 0; k < KK; k++) {
            float vx = wave_sum(s[k] * p.x);
            float vy = wave_sum(s[k] * p.y);
            if (lane == 0) {
                atomicAdd(&ws[256 + b0 * 32 + k * 2],     vx);
                atomicAdd(&ws[256 + b0 * 32 + k * 2 + 1], vy);
            }
        }
        float e = wave_sum(ent);
        if (lane == 0) atomicAdd(&ws[768], e);
    } else {
#pragma unroll
        for (int k = 0; k < KK; k++) {
            atomicAdd(&ws[bi * KK + k], s[k]);
            atomicAdd(&ws[256 + bi * 32 + k * 2],     s[k] * p.x);
            atomicAdd(&ws[256 + bi * 32 + k * 2 + 1], s[k] * p.y);
        }
        atomicAdd(&ws[768], ent);
    }
}

#define POOL_NODES 128

__global__ __launch_bounds__(256) void k_pool(
    const float* __restrict__ x, const void* __restrict__ batch,
    const float* __restrict__ s, float* __restrict__ out,
    const float* __restrict__ ws)
{
    const int n0 = blockIdx.x * POOL_NODES;
    const int c = threadIdx.x & (CCH - 1);
    const int kg = __builtin_amdgcn_readfirstlane(threadIdx.x >> 7);  // 0 or 1, wave-uniform
    const int is64 = (int)ws[769];

    float racc[8];
#pragma unroll
    for (int i = 0; i < 8; i++) racc[i] = 0.0f;

    int curb = load_batch(batch, n0, is64);

#pragma unroll 4
    for (int t = 0; t < POOL_NODES; t++) {
        const int n = n0 + t;
        const int bn = load_batch(batch, n, is64);
        if (bn != curb) {
#pragma unroll
            for (int i = 0; i < 8; i++) {
                atomicAdd(&out[curb * (KK * CCH) + (kg * 8 + i) * CCH + c], racc[i]);
                racc[i] = 0.0f;
            }
            curb = bn;
        }
        const float xvv = x[(size_t)n * CCH + c];
        const float* srow = s + (size_t)n * KK + kg * 8;  // uniform address -> s_load
#pragma unroll
        for (int i = 0; i < 8; i++) racc[i] = fmaf(srow[i], xvv, racc[i]);
    }
#pragma unroll
    for (int i = 0; i < 8; i++)
        atomicAdd(&out[curb * (KK * CCH) + (kg * 8 + i) * CCH + c], racc[i]);
}

__global__ __launch_bounds__(256) void k_final(
    const float* __restrict__ ws, const float* __restrict__ active_mask,
    float* __restrict__ mu_out, float* __restrict__ losses)
{
    __shared__ float sums[256];
    __shared__ float smu[512];
    __shared__ float savg[16];
    __shared__ float red[256];
    const int tid = threadIdx.x;

    sums[tid] = ws[tid];
    __syncthreads();

    if (tid < 16) {
        float a = 0.0f;
#pragma unroll
        for (int b = 0; b < 16; b++) a += sums[b * 16 + tid];
        savg[tid] = a / (float)NN;
    }
    for (int i = tid; i < 512; i += 256) {
        int sk = i >> 1;   // b*16+k
        float v = ws[256 + i] / (sums[sk] + EPSF);
        smu[i] = v;
        mu_out[i] = v;
    }
    __syncthreads();

    float rep = 0.0f;
    for (int t = tid; t < 4096; t += 256) {
        int b = t >> 8, i = (t >> 4) & 15, j = t & 15;
        if (i != j) {
            float dx = smu[b * 32 + i * 2]     - smu[b * 32 + j * 2];
            float dy = smu[b * 32 + i * 2 + 1] - smu[b * 32 + j * 2 + 1];
            rep += 1.0f / (dx * dx + dy * dy + 1.0f);
        }
    }
    red[tid] = rep;
    __syncthreads();
    for (int st = 128; st > 0; st >>= 1) {
        if (tid < st) red[tid] += red[tid + st];
        __syncthreads();
    }

    if (tid == 0) {
        const float p = 1.0f / 16.0f;
        float separation = red[0] / (float)(16 * 15);
        float entropy = -ws[768] / (float)NN;
        float diversity = 0.f, pruning = 0.f, amsum = 0.f, collapse = 0.f, mean = 0.f;
        for (int k = 0; k < 16; k++) {
            float a = savg[k];
            diversity += p * logf(p / (a + EPSF));
            pruning += fabsf(a * (1.0f - active_mask[k]));
            amsum += active_mask[k];
            collapse += (a - p) * (a - p);
            mean += a;
        }
        pruning /= 16.0f;
        mean /= 16.0f;
        float var = 0.f;
        for (int k = 0; k < 16; k++) { float d = savg[k] - mean; var += d * d; }
        float balance = sqrtf(var / 16.0f);
        float sparsity = (amsum / 16.0f) * 0.01f;
        collapse *= 2.0f;
        losses[0] = entropy;   losses[1] = diversity; losses[2] = 0.0f;
        losses[3] = pruning;   losses[4] = sparsity;  losses[5] = 0.0f;
        losses[6] = collapse;  losses[7] = balance;   losses[8] = separation;
    }
}

extern "C" void kernel_launch(void* const* d_in, const int* in_sizes, int n_in,
                              void* d_out, int out_size, void* d_ws, size_t ws_size,
                              hipStream_t stream) {
    const float* x       = (const float*)d_in[0];
    const void*  batch   = d_in[1];
    const float* pos     = (const float*)d_in[2];
    const float* gumbel  = (const float*)d_in[3];
    const float* W1      = (const float*)d_in[4];
    const float* b1      = (const float*)d_in[5];
    const float* W2      = (const float*)d_in[6];
    const float* b2      = (const float*)d_in[7];
    const float* scaling = (const float*)d_in[8];
    const float* am      = (const float*)d_in[9];

    float* out      = (float*)d_out;
    float* s_sec    = out + OFF_S;
    float* mu_sec   = out + OFF_MU;
    float* loss_sec = out + OFF_L;
    float* wsf      = (float*)d_ws;

    k_detect<<<1, 64, 0, stream>>>((const int*)batch, wsf + 769);
    k_zero<<<128, 256, 0, stream>>>(out, wsf);
    k_mlp<<<NN / 256, 256, 0, stream>>>(x, batch, pos, gumbel, W1, b1, W2, b2,
                                        scaling, am, s_sec, wsf);
    k_pool<<<NN / POOL_NODES, 256, 0, stream>>>(x, batch, s_sec, out, wsf);
    k_final<<<1, 256, 0, stream>>>(wsf, am, mu_sec, loss_sec);
}